// Round 15
// baseline (227.346 us; speedup 1.0000x reference)
//
#include <hip/hip_runtime.h>
#include <hip/hip_bf16.h>
#include <stdint.h>

// LNLinearSigmoid: LayerNorm(x) @ W^T -> sigmoid
// Round 15: R14 (B direct global->VGPR, A-only LDS dbuf) with the sync race
// FIXED: the A-stage drain VMC executes BEFORE the end-of-tile barrier
// (drain-before-barrier invariant; vmcnt is per-wave, so cross-wave
// visibility requires VMC -> BARR order). B-load and ds_read waits are left
// to the compiler (register deps -> precise counted waits). bn = bid0&7
// pins one 1MB B panel per XCD L2. ws >= 75.5 MB.

typedef __attribute__((ext_vector_type(4))) float f32x4;
typedef __attribute__((ext_vector_type(8))) __bf16 b16x8;

__device__ __forceinline__ void async16(void* lds_p, const void* g) {
  __builtin_amdgcn_global_load_lds(
      (const __attribute__((address_space(1))) void*)g,
      (__attribute__((address_space(3))) void*)lds_p, 16, 0, 0);
}

__device__ __forceinline__ unsigned short f2bf(float f) {
  uint32_t u = __float_as_uint(f);
  u += 0x7FFFu + ((u >> 16) & 1u);
  return (unsigned short)(u >> 16);
}

// ---------------- LN (blocks 0..16383) + W conv (blocks 16384..20479) ------
__global__ __launch_bounds__(256) void ln_wconv_kernel(
    const float* __restrict__ x, unsigned short* __restrict__ xn,
    const float* __restrict__ W, unsigned short* __restrict__ Wb) {
  const int t = threadIdx.x;
  if (blockIdx.x >= 16384) {
    const size_t i = (size_t)(blockIdx.x - 16384) * 256 + t;
    float4 v = ((const float4*)W)[i];
    ushort4 o;
    o.x = f2bf(v.x); o.y = f2bf(v.y); o.z = f2bf(v.z); o.w = f2bf(v.w);
    ((ushort4*)Wb)[i] = o;
    return;
  }
  const int row = blockIdx.x;
  const float4* xr = (const float4*)(x + (size_t)row * 2048);
  float4 a = xr[t];
  float4 b = xr[t + 256];
  float s = a.x + a.y + a.z + a.w + b.x + b.y + b.z + b.w;
  float q = a.x * a.x + a.y * a.y + a.z * a.z + a.w * a.w +
            b.x * b.x + b.y * b.y + b.z * b.z + b.w * b.w;
#pragma unroll
  for (int off = 32; off > 0; off >>= 1) {
    s += __shfl_down(s, off);
    q += __shfl_down(q, off);
  }
  __shared__ float red[8];
  const int w = t >> 6;
  if ((t & 63) == 0) { red[w] = s; red[4 + w] = q; }
  __syncthreads();
  s = red[0] + red[1] + red[2] + red[3];
  q = red[4] + red[5] + red[6] + red[7];
  const float mean = s * (1.0f / 2048.0f);
  const float var = fmaxf(q * (1.0f / 2048.0f) - mean * mean, 0.0f);
  const float scl = rsqrtf(var + 1e-5f);
  ushort4 o0, o1;
  o0.x = f2bf((a.x - mean) * scl);
  o0.y = f2bf((a.y - mean) * scl);
  o0.z = f2bf((a.z - mean) * scl);
  o0.w = f2bf((a.w - mean) * scl);
  o1.x = f2bf((b.x - mean) * scl);
  o1.y = f2bf((b.y - mean) * scl);
  o1.z = f2bf((b.z - mean) * scl);
  o1.w = f2bf((b.w - mean) * scl);
  ushort4* orow = (ushort4*)(xn + (size_t)row * 2048);
  orow[t] = o0;
  orow[t + 256] = o1;
}

// ---------------- 256x256 GEMM: A in LDS (dbuf 64KB), B in registers -------
// Per K-tile t (reads cur; stages A(t+1)->nxt):
//   LDA8 S0 (A(t) landed: VMC(8)+BARR at t-1)
//   STG_A(nxt) x4
//   MFMA S0a | LDA8 S1 | MFMA S0b | LDG B(t+1)S0 | MFMA S1 | LDG B(t+1)S1
//   VMC(8)  <- drains A-stage (outstanding: Astage4 + B(t+1) 8)
//   BARR    <- now all waves' A(t+1) writes visible; cur reads all retired
// Compiler inserts precise vmcnt for B-reg deps and lgkmcnt for ds_reads.
// bn = bid0 & 7 = XCD (round-robin dispatch) -> one B panel per L2.

#define STG_A(BOFF, h, kt)                                             \
  do {                                                                 \
    const char* s_ = pA + (size_t)((h) * 128) * 4096 + (kt) * 128;     \
    char* d_ = lds + (BOFF) + (h) * 16384 + tid * 16;                  \
    async16(d_, s_);                                                   \
    async16(d_ + 8192, s_ + 64 * 4096);                                \
  } while (0)

#define LDA8(BOFF, DST, S)                                             \
  do {                                                                 \
    _Pragma("unroll") for (int m_ = 0; m_ < 8; ++m_) {                 \
      const char* p_ = lds + (BOFF) + (m_ >> 2) * 16384 + abase +      \
                       (m_ & 3) * 2048;                                \
      DST[m_] = *(const b16x8*)(p_ + ((S) ? cs1 : cs0));               \
    }                                                                  \
  } while (0)

#define LDG_B_S(KT, S)                                                 \
  do {                                                                 \
    bF[0][S] = *(const b16x8*)(pBv + (size_t)(KT) * 128 + (S) * 64);   \
    bF[1][S] = *(const b16x8*)(pBv + 65536 + (size_t)(KT) * 128 + (S) * 64); \
    bF[2][S] = *(const b16x8*)(pBv + 524288 + (size_t)(KT) * 128 + (S) * 64); \
    bF[3][S] = *(const b16x8*)(pBv + 589824 + (size_t)(KT) * 128 + (S) * 64); \
  } while (0)

#define MFMA_MN(AF, MLO, MHI, S)                                       \
  do {                                                                 \
    _Pragma("unroll") for (int m_ = (MLO); m_ < (MHI); ++m_) {         \
      _Pragma("unroll") for (int n_ = 0; n_ < 4; ++n_) {               \
        acc[m_][n_] = __builtin_amdgcn_mfma_f32_16x16x32_bf16(         \
            AF[m_], bF[n_][S], acc[m_][n_], 0, 0, 0);                  \
      }                                                                \
    }                                                                  \
  } while (0)

#define BARR                                                           \
  do {                                                                 \
    __builtin_amdgcn_s_barrier();                                      \
    asm volatile("" ::: "memory");                                     \
  } while (0)

#define SB0 __builtin_amdgcn_sched_barrier(0)
#define VMC(n) asm volatile("s_waitcnt vmcnt(" #n ")" ::: "memory")

__global__ __launch_bounds__(512, 2) void gemm_bd(
    const unsigned short* __restrict__ A, const unsigned short* __restrict__ B,
    float* __restrict__ C) {
  __shared__ __align__(16) char lds[65536];

  const int bid0 = blockIdx.x;     // 512 blocks
  const int bn = bid0 & 7;         // = XCD under round-robin dispatch
  const int bm = bid0 >> 3;        // 0..63; 8 consecutive blocks share bm

  const int tid = threadIdx.x;
  const int w = tid >> 6, l = tid & 63;
  const int wr = w >> 2, wc = w & 3;
  const int fr = l & 15, fg = l >> 4;

  // A staging source (linear LDS dest, inverse-swizzled global source)
  const int arow = tid >> 3;
  const int swz = ((tid & 7) << 4) ^ ((arow & 7) << 4);
  const char* pA = (const char*)A + (size_t)(bm * 256 + arow) * 4096 + swz;

  // B direct-global lane base: row = bn*256 + wc*32 + fr; frag n adds
  // (n>>1)*128 rows (=524288 B) and (n&1)*16 rows (=65536 B); byte fg*16.
  const char* pBv =
      (const char*)B + (size_t)(bn * 256 + wc * 32 + fr) * 4096 + fg * 16;

  // A ds_read offsets (proven zero-conflict swizzle)
  const int cswz = (fg << 4) ^ ((fr & 7) << 4);
  const int cs0 = cswz, cs1 = cswz ^ 64;
  const int abase = (wr * 64 + fr) * 128;

  f32x4 acc[8][4] = {};
  b16x8 aFa[8], aFb[8], bF[4][2];

  // prologue: A(0) -> buf0 (4 async16), B(0) -> regs (8 loads);
  // drain A-stage BEFORE the barrier (cross-wave visibility).
  STG_A(0, 0, 0); STG_A(0, 1, 0);
  LDG_B_S(0, 0); LDG_B_S(0, 1);
  VMC(8);                                  // leaves the 8 B loads in flight
  BARR;

#pragma unroll 1
  for (int t = 0; t < 32; ++t) {
    const int cur = (t & 1) << 15;        // 0 / 32768
    const int nxt = 32768 - cur;
    const bool s2 = (t < 31);

    LDA8(cur, aFa, 0);                     // A(t) landed (VMC+BARR at t-1)
    if (s2) { STG_A(nxt, 0, t + 1); STG_A(nxt, 1, t + 1); }
    MFMA_MN(aFa, 0, 4, 0);                 // 16 MFMA (compiler waits B-S0)
    SB0; LDA8(cur, aFb, 1); SB0;
    MFMA_MN(aFa, 4, 8, 0);                 // 16 MFMA
    if (s2) { SB0; LDG_B_S(t + 1, 0); SB0; }
    MFMA_MN(aFb, 0, 8, 1);                 // 32 MFMA (compiler waits B-S1)
    if (s2) { SB0; LDG_B_S(t + 1, 1); SB0; }
    if (s2) {
      VMC(8);   // outstanding: Astage 4 + B(t+1) 8 -> drains Astage exactly
      BARR;     // all waves' A(t+1) visible; all cur reads retired pre-BARR
    }
  }

  // epilogue: sigmoid + store. C/D frag: row = fg*4 + r, col = fr.
  float* gC = C + (size_t)(bm * 256) * 2048 + bn * 256;
#pragma unroll
  for (int m = 0; m < 8; ++m) {
#pragma unroll
    for (int n = 0; n < 4; ++n) {
      const int col = (n >> 1) * 128 + wc * 32 + (n & 1) * 16 + fr;
#pragma unroll
      for (int r = 0; r < 4; ++r) {
        const int row = (m >> 2) * 128 + wr * 64 + (m & 3) * 16 + fg * 4 + r;
        const float y = acc[m][n][r];
        gC[(size_t)row * 2048 + col] =
            __builtin_amdgcn_rcpf(1.0f + __expf(-y));
      }
    }
  }
}

extern "C" void kernel_launch(void* const* d_in, const int* in_sizes, int n_in,
                              void* d_out, int out_size, void* d_ws, size_t ws_size,
                              hipStream_t stream) {
  const float* x = (const float*)d_in[0];
  const float* W = (const float*)d_in[1];
  float* out = (float*)d_out;

  unsigned short* xnb = (unsigned short*)d_ws;
  unsigned short* Wb =
      (unsigned short*)((char*)d_ws + (size_t)16384 * 2048 * 2);

  ln_wconv_kernel<<<16384 + 4096, 256, 0, stream>>>(x, xnb, W, Wb);
  gemm_bd<<<512, 512, 0, stream>>>(xnb, Wb, out);
}

// Round 16
// 158.653 us; speedup vs baseline: 1.4330x; 1.4330x over previous
//
#include <hip/hip_runtime.h>
#include <hip/hip_bf16.h>
#include <stdint.h>

// LNLinearSigmoid: LayerNorm(x) @ W^T -> sigmoid
// Round 16 = R13 champion verbatim (best verified: 158.8 us total).
// LN->bf16 + W->bf16 (one dispatch, BW-floor), then 256x256-tile 8-phase
// bf16 MFMA GEMM: 1 barrier/phase, counted lgkm heads, vmcnt(6) ledger,
// zero-conflict XOR LDS swizzle (both-sides), XCD blockIdx swizzle,
// no setprio (m190: negative on lockstep structures), ds_reads inside
// MFMA clusters, sigmoid epilogue. ws >= 75.5 MB.

typedef __attribute__((ext_vector_type(4))) float f32x4;
typedef __attribute__((ext_vector_type(8))) __bf16 b16x8;

__device__ __forceinline__ void async16(void* lds_p, const void* g) {
  __builtin_amdgcn_global_load_lds(
      (const __attribute__((address_space(1))) void*)g,
      (__attribute__((address_space(3))) void*)lds_p, 16, 0, 0);
}

__device__ __forceinline__ unsigned short f2bf(float f) {
  uint32_t u = __float_as_uint(f);
  u += 0x7FFFu + ((u >> 16) & 1u);
  return (unsigned short)(u >> 16);
}

// ---------------- LN (blocks 0..16383) + W conv (blocks 16384..20479) ------
__global__ __launch_bounds__(256) void ln_wconv_kernel(
    const float* __restrict__ x, unsigned short* __restrict__ xn,
    const float* __restrict__ W, unsigned short* __restrict__ Wb) {
  const int t = threadIdx.x;
  if (blockIdx.x >= 16384) {
    const size_t i = (size_t)(blockIdx.x - 16384) * 256 + t;
    float4 v = ((const float4*)W)[i];
    ushort4 o;
    o.x = f2bf(v.x); o.y = f2bf(v.y); o.z = f2bf(v.z); o.w = f2bf(v.w);
    ((ushort4*)Wb)[i] = o;
    return;
  }
  const int row = blockIdx.x;
  const float4* xr = (const float4*)(x + (size_t)row * 2048);
  float4 a = xr[t];
  float4 b = xr[t + 256];
  float s = a.x + a.y + a.z + a.w + b.x + b.y + b.z + b.w;
  float q = a.x * a.x + a.y * a.y + a.z * a.z + a.w * a.w +
            b.x * b.x + b.y * b.y + b.z * b.z + b.w * b.w;
#pragma unroll
  for (int off = 32; off > 0; off >>= 1) {
    s += __shfl_down(s, off);
    q += __shfl_down(q, off);
  }
  __shared__ float red[8];
  const int w = t >> 6;
  if ((t & 63) == 0) { red[w] = s; red[4 + w] = q; }
  __syncthreads();
  s = red[0] + red[1] + red[2] + red[3];
  q = red[4] + red[5] + red[6] + red[7];
  const float mean = s * (1.0f / 2048.0f);
  const float var = fmaxf(q * (1.0f / 2048.0f) - mean * mean, 0.0f);
  const float scl = rsqrtf(var + 1e-5f);
  ushort4 o0, o1;
  o0.x = f2bf((a.x - mean) * scl);
  o0.y = f2bf((a.y - mean) * scl);
  o0.z = f2bf((a.z - mean) * scl);
  o0.w = f2bf((a.w - mean) * scl);
  o1.x = f2bf((b.x - mean) * scl);
  o1.y = f2bf((b.y - mean) * scl);
  o1.z = f2bf((b.z - mean) * scl);
  o1.w = f2bf((b.w - mean) * scl);
  ushort4* orow = (ushort4*)(xn + (size_t)row * 2048);
  orow[t] = o0;
  orow[t + 256] = o1;
}

// ---------------- 256x256 8-phase GEMM (champion schedule) -----------------
// LDS: buf*65536 + {A0:0, A1:16K, B0:32K, B1:48K}. Regions 128 rows x 128B.
// Stage map: P1:A1->buf1(t1) P2:B0->buf0(t2) P3:A0->buf0(t2) P4:B1->buf0(t2)
//   P5:A1->buf0(t2) P6:B0->buf1(t3) P7:A0->buf1(t3) P8:B1->buf1(t3).
// vmcnt(6) at P4/P8 mid-cluster. Counted lgkm heads:
//   enter P1: 12 -> lgkm(6), pre-S1 lgkm(2); P2: 4 -> lgkm(2)/lgkm(4);
//   P3: 8 -> lgkm(4)/lgkm(0); P4: 0 -> free. P5..P8 mirror.

#define STG_A(buf, h, kt)                                              \
  do {                                                                 \
    const char* s_ = pA + (size_t)((h) * 128) * 4096 + (kt) * 128;     \
    char* d_ = lds + (buf) * 65536 + (h) * 16384 + tid * 16;           \
    async16(d_, s_);                                                   \
    async16(d_ + 8192, s_ + 64 * 4096);                                \
  } while (0)

#define STG_B(buf, h, kt)                                              \
  do {                                                                 \
    const char* s_ = pB + (size_t)((h) * 128) * 4096 + (kt) * 128;     \
    char* d_ = lds + 32768 + (buf) * 65536 + (h) * 16384 + tid * 16;   \
    async16(d_, s_);                                                   \
    async16(d_ + 8192, s_ + 64 * 4096);                                \
  } while (0)

#define LDA_S(buf, qm, S)                                              \
  do {                                                                 \
    _Pragma("unroll") for (int i_ = 0; i_ < 4; ++i_) {                 \
      const char* p_ = lds + (buf) * 65536 + (qm) * 16384 + abase + i_ * 2048; \
      aF[i_][S] = *(const b16x8*)(p_ + ((S) ? cs1 : cs0));             \
    }                                                                  \
  } while (0)

#define LDB_S(dstf, buf, qn, S)                                        \
  do {                                                                 \
    _Pragma("unroll") for (int j_ = 0; j_ < 2; ++j_) {                 \
      const char* p_ = lds + (buf) * 65536 + (qn) * 16384 + bbase + j_ * 2048; \
      dstf[j_][S] = *(const b16x8*)(p_ + ((S) ? cs1 : cs0));           \
    }                                                                  \
  } while (0)

#define MFMA_H(qm, qn, BF, S)                                          \
  do {                                                                 \
    _Pragma("unroll") for (int i_ = 0; i_ < 4; ++i_) {                 \
      _Pragma("unroll") for (int j_ = 0; j_ < 2; ++j_) {               \
        acc[(qm) * 4 + i_][(qn) * 2 + j_] =                            \
            __builtin_amdgcn_mfma_f32_16x16x32_bf16(                   \
                aF[i_][S], BF[j_][S], acc[(qm) * 4 + i_][(qn) * 2 + j_], 0, 0, 0); \
      }                                                                \
    }                                                                  \
  } while (0)

#define BARR                                                           \
  do {                                                                 \
    __builtin_amdgcn_s_barrier();                                      \
    asm volatile("" ::: "memory");                                     \
  } while (0)

#define LGKM(n)                                                        \
  do {                                                                 \
    asm volatile("s_waitcnt lgkmcnt(" #n ")" ::: "memory");            \
    __builtin_amdgcn_sched_barrier(0);                                 \
  } while (0)

#define SB0 __builtin_amdgcn_sched_barrier(0)
#define VMC(n) asm volatile("s_waitcnt vmcnt(" #n ")" ::: "memory")

__global__ __launch_bounds__(512, 2) void gemm8p(
    const unsigned short* __restrict__ A, const unsigned short* __restrict__ B,
    float* __restrict__ C) {
  __shared__ __align__(16) char lds[131072];

  const int bid0 = blockIdx.x;                       // 512 blocks
  const int bid = (bid0 & 7) * 64 + (bid0 >> 3);     // XCD swizzle (512%8==0)
  const int bm = bid >> 3;                           // 0..63
  const int bn = bid & 7;                            // 0..7

  const int tid = threadIdx.x;
  const int w = tid >> 6, l = tid & 63;
  const int wr = w >> 2, wc = w & 3;
  const int fr = l & 15, fg = l >> 4;

  // staging source (linear LDS dest, inverse-swizzled global source)
  const int arow = tid >> 3;
  const int swz = ((tid & 7) << 4) ^ ((arow & 7) << 4);
  const char* pA = (const char*)A + (size_t)(bm * 256 + arow) * 4096 + swz;
  const char* pB = (const char*)B + (size_t)(bn * 256 + arow) * 4096 + swz;

  // ds_read offsets (proven zero-conflict swizzle)
  const int cswz = (fg << 4) ^ ((fr & 7) << 4);
  const int cs0 = cswz, cs1 = cswz ^ 64;
  const int abase = (wr * 64 + fr) * 128;
  const int bbase = 32768 + (wc * 32 + fr) * 128;

  f32x4 acc[8][4] = {};
  b16x8 aF[4][2], bF0[2][2], bF1[2][2];

  // prologue: t0 full -> buf0; t1: B0,A0,B1 -> buf1
  STG_A(0, 0, 0); STG_B(0, 0, 0); STG_B(0, 1, 0); STG_A(0, 1, 0);
  STG_B(1, 0, 1); STG_A(1, 0, 1); STG_B(1, 1, 1);
  VMC(6);
  BARR;
  // P1@it0 operands, issue order matching steady-state P8 pattern:
  LDA_S(0, 0, 0); LDB_S(bF0, 0, 0, 0);   // "mid" 6
  LDA_S(0, 0, 1); LDB_S(bF0, 0, 0, 1);   // "tail" 6

#pragma unroll 1
  for (int it = 0; it < 16; ++it) {
    const int t1 = 2 * it + 1, t2 = 2 * it + 2, t3 = 2 * it + 3;
    const bool s2 = (it < 15);

    // P1: Q(0,0) buf0, B=bF0. [enter: 12 outstanding]
    STG_A(1, 1, t1);
    BARR; LGKM(6);
    MFMA_H(0, 0, bF0, 0);
    SB0; LDB_S(bF1, 0, 1, 0); LGKM(2);
    MFMA_H(0, 0, bF0, 1);
    SB0; LDB_S(bF1, 0, 1, 1);

    // P2: Q(0,1) buf0, B=bF1. [enter: 4]
    if (s2) STG_B(0, 0, t2);
    BARR; LGKM(2);
    MFMA_H(0, 1, bF1, 0);
    SB0; LDA_S(0, 1, 0); LGKM(4);
    MFMA_H(0, 1, bF1, 1);
    SB0; LDA_S(0, 1, 1);

    // P3: Q(1,1) buf0, B=bF1 (aF = buf0.A1). [enter: 8]
    if (s2) STG_A(0, 0, t2);
    BARR; LGKM(4);
    MFMA_H(1, 1, bF1, 0);
    LGKM(0);
    MFMA_H(1, 1, bF1, 1);

    // P4: Q(1,0) buf0, B=bF0. [enter: 0] Mid: VMC; aF<-buf1.A0, bF1<-buf1.B0.
    if (s2) STG_B(0, 1, t2);
    BARR;
    MFMA_H(1, 0, bF0, 0);
    if (s2) { VMC(6); } else { VMC(0); }
    SB0; LDA_S(1, 0, 0); LDB_S(bF1, 1, 0, 0); SB0;
    MFMA_H(1, 0, bF0, 1);
    SB0; LDA_S(1, 0, 1); LDB_S(bF1, 1, 0, 1);

    // P5: Q(0,0) buf1, B=bF1. [enter: 12]
    if (s2) STG_A(0, 1, t2);
    BARR; LGKM(6);
    MFMA_H(0, 0, bF1, 0);
    SB0; LDB_S(bF0, 1, 1, 0); LGKM(2);
    MFMA_H(0, 0, bF1, 1);
    SB0; LDB_S(bF0, 1, 1, 1);

    // P6: Q(0,1) buf1, B=bF0. [enter: 4]
    if (s2) STG_B(1, 0, t3);
    BARR; LGKM(2);
    MFMA_H(0, 1, bF0, 0);
    SB0; LDA_S(1, 1, 0); LGKM(4);
    MFMA_H(0, 1, bF0, 1);
    SB0; LDA_S(1, 1, 1);

    // P7: Q(1,1) buf1, B=bF0. [enter: 8]
    if (s2) STG_A(1, 0, t3);
    BARR; LGKM(4);
    MFMA_H(1, 1, bF0, 0);
    LGKM(0);
    MFMA_H(1, 1, bF0, 1);

    // P8: Q(1,0) buf1, B=bF1. [enter: 0] Mid: VMC(6); aF<-buf0.A0, bF0<-buf0.B0.
    if (s2) STG_B(1, 1, t3);
    BARR;
    MFMA_H(1, 0, bF1, 0);
    if (s2) { VMC(6); SB0; LDA_S(0, 0, 0); LDB_S(bF0, 0, 0, 0); SB0; }
    MFMA_H(1, 0, bF1, 1);
    if (s2) { SB0; LDA_S(0, 0, 1); LDB_S(bF0, 0, 0, 1); }
  }

  // epilogue: sigmoid + store. C/D frag: row = fg*4 + r, col = fr.
  float* gC = C + (size_t)(bm * 256) * 2048 + bn * 256;
#pragma unroll
  for (int qm = 0; qm < 2; ++qm) {
#pragma unroll
    for (int i = 0; i < 4; ++i) {
#pragma unroll
      for (int qn = 0; qn < 2; ++qn) {
#pragma unroll
        for (int j = 0; j < 2; ++j) {
#pragma unroll
          for (int r = 0; r < 4; ++r) {
            const int row = qm * 128 + wr * 64 + i * 16 + fg * 4 + r;
            const int col = qn * 128 + wc * 32 + j * 16 + fr;
            const float y = acc[qm * 4 + i][qn * 2 + j][r];
            gC[(size_t)row * 2048 + col] =
                __builtin_amdgcn_rcpf(1.0f + __expf(-y));
          }
        }
      }
    }
  }
}

extern "C" void kernel_launch(void* const* d_in, const int* in_sizes, int n_in,
                              void* d_out, int out_size, void* d_ws, size_t ws_size,
                              hipStream_t stream) {
  const float* x = (const float*)d_in[0];
  const float* W = (const float*)d_in[1];
  float* out = (float*)d_out;

  unsigned short* xnb = (unsigned short*)d_ws;
  unsigned short* Wb =
      (unsigned short*)((char*)d_ws + (size_t)16384 * 2048 * 2);

  ln_wconv_kernel<<<16384 + 4096, 256, 0, stream>>>(x, xnb, W, Wb);
  gemm8p<<<512, 512, 0, stream>>>(xnb, Wb, out);
}